// Round 2
// baseline (55.798 us; speedup 1.0000x reference)
//
#include <hip/hip_runtime.h>

// JPEG decompress: dequant -> 8x8 IDCT -> merge -> chroma 2x upsample -> YCbCr->RGB -> clip
// B=16, H=W=1024. Y blocks: [16,16384,8,8]; Cb/Cr: [16,4096,8,8]. Out: [16,3,1024,1024] f32.
//
// One 256-thread block per (b, 64x16 output tile):
//   16 Y blocks (8x2) + 4 Cb + 4 Cr blocks, IDCT'd in LDS (stride-72 padded),
//   fused upsample + color conversion + clip, float4 stores.
// 1D grid (16384 blocks): bid = b*1024 + ty*16 + tx  (avoids 3D-grid graph-replay quirks).

static __device__ __forceinline__ float clamp255(float v) {
    return fminf(fmaxf(v, 0.0f), 255.0f);
}

// A[y][v] = alpha[y] * cos((2v+1)*y*pi/16)  (IDCT basis, alpha folded)
#define C1 0.98078528040323044913f
#define C2 0.92387953251128675613f
#define C3 0.83146961230254523708f
#define C4 0.70710678118654752440f
#define C5 0.55557023301960222474f
#define C6 0.38268343236508977173f
#define C7 0.19509032201612826785f

__global__ __launch_bounds__(256) void decompress_jpeg_18021682774939_kernel(
    const float* __restrict__ yq, const float* __restrict__ cbq,
    const float* __restrict__ crq, const float* __restrict__ ytab,
    const float* __restrict__ ctab, float* __restrict__ out)
{
    constexpr float A8[8][8] = {
        { C4,  C4,  C4,  C4,  C4,  C4,  C4,  C4},
        { C1,  C3,  C5,  C7, -C7, -C5, -C3, -C1},
        { C2,  C6, -C6, -C2, -C2, -C6,  C6,  C2},
        { C3, -C7, -C1, -C5,  C5,  C1,  C7, -C3},
        { C4, -C4, -C4,  C4,  C4, -C4, -C4,  C4},
        { C5, -C1,  C7,  C3, -C3, -C7,  C1, -C5},
        { C6, -C2,  C2, -C6, -C6,  C2, -C2,  C6},
        { C7, -C5,  C3, -C1,  C1, -C3,  C5, -C7},
    };

    // 24 blocks (16 Y + 4 Cb + 4 Cr), each 8x8 padded to 72 words (288B, 16B-aligned)
    __shared__ __align__(16) float blk[24 * 72];

    const int t   = threadIdx.x;
    const int bid = blockIdx.x;        // 0..16383
    const int tx  = bid & 15;          // 0..15  (64-px wide tiles)
    const int ty  = (bid >> 4) & 63;   // 0..63  (16-px tall tiles)
    const int b   = bid >> 10;         // 0..15

    // ---- load + dequant into LDS ----
    {
        // Y: 16 blocks = 256 float4; one per thread
        const int f   = t & 127;      // float4 idx within a row of 8 blocks
        const int byr = t >> 7;       // block-row within tile (0/1)
        const int bx  = f >> 4;       // block-col within tile (0..7)
        const int e4  = f & 15;       // float4 idx within block
        const int nb  = (ty * 2 + byr) * 128 + tx * 8 + bx;
        float4 d = reinterpret_cast<const float4*>(yq)[(size_t)(b * 16384 + nb) * 16 + e4];
        float4 q = reinterpret_cast<const float4*>(ytab)[e4];
        d.x *= q.x; d.y *= q.y; d.z *= q.z; d.w *= q.w;
        const int lid = byr * 8 + bx;
        *reinterpret_cast<float4*>(&blk[lid * 72 + e4 * 4]) = d;
    }
    if (t < 128) {
        // chroma: 4 Cb blocks (threads 0..63) + 4 Cr blocks (threads 64..127)
        const int comp = t >> 6;
        const int tt   = t & 63;
        const int bx   = tt >> 4;
        const int e4   = tt & 15;
        const int nc   = ty * 64 + tx * 4 + bx;   // chroma block grid is 64x64
        const float* src = comp ? crq : cbq;
        float4 d = reinterpret_cast<const float4*>(src)[(size_t)(b * 4096 + nc) * 16 + e4];
        float4 q = reinterpret_cast<const float4*>(ctab)[e4];
        d.x *= q.x; d.y *= q.y; d.z *= q.z; d.w *= q.w;
        const int lid = 16 + comp * 4 + bx;
        *reinterpret_cast<float4*>(&blk[lid * 72 + e4 * 4]) = d;
    }
    __syncthreads();

    // ---- IDCT stage 1: t1[x][v] = sum_y X[x][y] * A8[y][v]   (thread owns row x) ----
    if (t < 192) {
        const int blki = t >> 3, x = t & 7;
        float* row = &blk[blki * 72 + x * 8];
        float4 r0 = *reinterpret_cast<float4*>(row);
        float4 r1 = *reinterpret_cast<float4*>(row + 4);
        const float xs[8] = {r0.x, r0.y, r0.z, r0.w, r1.x, r1.y, r1.z, r1.w};
        float acc[8] = {0.f, 0.f, 0.f, 0.f, 0.f, 0.f, 0.f, 0.f};
        #pragma unroll
        for (int yy = 0; yy < 8; ++yy) {
            #pragma unroll
            for (int v = 0; v < 8; ++v)
                acc[v] = fmaf(xs[yy], A8[yy][v], acc[v]);
        }
        *reinterpret_cast<float4*>(row)     = make_float4(acc[0], acc[1], acc[2], acc[3]);
        *reinterpret_cast<float4*>(row + 4) = make_float4(acc[4], acc[5], acc[6], acc[7]);
    }
    __syncthreads();

    // ---- IDCT stage 2: out[u][v] = 0.25 * sum_x t1[x][v] * A8[x][u] + 128  (thread owns col v) ----
    if (t < 192) {
        const int blki = t >> 3, v = t & 7;
        float* base = &blk[blki * 72 + v];
        float tc[8];
        #pragma unroll
        for (int x = 0; x < 8; ++x) tc[x] = base[x * 8];
        float acc[8] = {0.f, 0.f, 0.f, 0.f, 0.f, 0.f, 0.f, 0.f};
        #pragma unroll
        for (int x = 0; x < 8; ++x) {
            #pragma unroll
            for (int u = 0; u < 8; ++u)
                acc[u] = fmaf(tc[x], A8[x][u], acc[u]);
        }
        #pragma unroll
        for (int u = 0; u < 8; ++u)
            base[u * 8] = fmaf(acc[u], 0.25f, 128.0f);
    }
    __syncthreads();

    // ---- fused upsample + YCbCr->RGB + clip + store (each thread: 4 px x 3 ch) ----
    const int row = t >> 4;            // 0..15 within tile
    const int c0  = (t & 15) * 4;      // 0..60 within tile
    const int ylid = (row >> 3) * 8 + (c0 >> 3);
    const float4 yv = *reinterpret_cast<float4*>(&blk[ylid * 72 + (row & 7) * 8 + (c0 & 7)]);
    const int crow = row >> 1;         // chroma row within block (0..7)
    const int ccol = c0 >> 1;          // chroma col within 32-wide region (even)
    const int cblk = ccol >> 3;        // 0..3
    const int ce   = crow * 8 + (ccol & 7);
    const float2 cbv = *reinterpret_cast<float2*>(&blk[(16 + cblk) * 72 + ce]);
    const float2 crv = *reinterpret_cast<float2*>(&blk[(20 + cblk) * 72 + ce]);

    const float ys[4]  = {yv.x, yv.y, yv.z, yv.w};
    const float cbs[4] = {cbv.x - 128.f, cbv.x - 128.f, cbv.y - 128.f, cbv.y - 128.f};
    const float crs[4] = {crv.x - 128.f, crv.x - 128.f, crv.y - 128.f, crv.y - 128.f};

    float r[4], g[4], bl[4];
    #pragma unroll
    for (int j = 0; j < 4; ++j) {
        r[j]  = clamp255(fmaf(1.402f, crs[j], ys[j]));
        g[j]  = clamp255(fmaf(-0.714136f, crs[j], fmaf(-0.344136f, cbs[j], ys[j])));
        bl[j] = clamp255(fmaf(1.772f, cbs[j], ys[j]));
    }

    const size_t plane4 = (size_t)(1024 * 1024) >> 2;
    const size_t px4 = (((size_t)(ty * 16 + row)) * 1024 + tx * 64 + c0) >> 2;
    float4* o = reinterpret_cast<float4*>(out);
    const size_t base4 = (size_t)b * 3 * plane4 + px4;
    o[base4]               = make_float4(r[0],  r[1],  r[2],  r[3]);
    o[base4 + plane4]      = make_float4(g[0],  g[1],  g[2],  g[3]);
    o[base4 + 2 * plane4]  = make_float4(bl[0], bl[1], bl[2], bl[3]);
}

extern "C" void kernel_launch(void* const* d_in, const int* in_sizes, int n_in,
                              void* d_out, int out_size, void* d_ws, size_t ws_size,
                              hipStream_t stream) {
    const float* y  = (const float*)d_in[0];
    const float* cb = (const float*)d_in[1];
    const float* cr = (const float*)d_in[2];
    const float* yt = (const float*)d_in[3];
    const float* ct = (const float*)d_in[4];
    float* out = (float*)d_out;

    // 1D grid: 16 batches x 64 tile-rows x 16 tile-cols = 16384 blocks of 256 threads
    decompress_jpeg_18021682774939_kernel<<<16384, 256, 0, stream>>>(y, cb, cr, yt, ct, out);
}

// Round 4
// 49.170 us; speedup vs baseline: 1.1348x; 1.1348x over previous
//
#include <hip/hip_runtime.h>

// JPEG decompress: dequant -> 8x8 IDCT -> merge -> chroma 2x upsample -> YCbCr->RGB -> clip
// B=16, H=W=1024. Y blocks: [16,16384,8,8]; Cb/Cr: [16,4096,8,8]. Out: [16,3,1024,1024] f32.
//
// One 256-thread block per (b, 64x16 output tile):
//   16 Y blocks (8x2) + 4 Cb + 4 Cr blocks, IDCT'd in LDS (stride-72 padded),
//   fused upsample + color conversion + clip, float4 NON-TEMPORAL stores
//   (output is write-once -> keep 100MB of inputs L3-resident across replays).
// 1D grid (16384 blocks): bid = b*1024 + ty*16 + tx.

typedef float floatx4 __attribute__((ext_vector_type(4)));  // native vec for nontemporal builtin

static __device__ __forceinline__ float clamp255(float v) {
    return fminf(fmaxf(v, 0.0f), 255.0f);
}

// A[y][v] = alpha[y] * cos((2v+1)*y*pi/16)  (IDCT basis, alpha folded)
#define C1 0.98078528040323044913f
#define C2 0.92387953251128675613f
#define C3 0.83146961230254523708f
#define C4 0.70710678118654752440f
#define C5 0.55557023301960222474f
#define C6 0.38268343236508977173f
#define C7 0.19509032201612826785f

__global__ __launch_bounds__(256) void decompress_jpeg_18021682774939_kernel(
    const float* __restrict__ yq, const float* __restrict__ cbq,
    const float* __restrict__ crq, const float* __restrict__ ytab,
    const float* __restrict__ ctab, float* __restrict__ out)
{
    constexpr float A8[8][8] = {
        { C4,  C4,  C4,  C4,  C4,  C4,  C4,  C4},
        { C1,  C3,  C5,  C7, -C7, -C5, -C3, -C1},
        { C2,  C6, -C6, -C2, -C2, -C6,  C6,  C2},
        { C3, -C7, -C1, -C5,  C5,  C1,  C7, -C3},
        { C4, -C4, -C4,  C4,  C4, -C4, -C4,  C4},
        { C5, -C1,  C7,  C3, -C3, -C7,  C1, -C5},
        { C6, -C2,  C2, -C6, -C6,  C2, -C2,  C6},
        { C7, -C5,  C3, -C1,  C1, -C3,  C5, -C7},
    };

    // 24 blocks (16 Y + 4 Cb + 4 Cr), each 8x8 padded to 72 words (288B, 16B-aligned)
    __shared__ __align__(16) float blk[24 * 72];

    const int t   = threadIdx.x;
    const int bid = blockIdx.x;        // 0..16383
    const int tx  = bid & 15;          // 0..15  (64-px wide tiles)
    const int ty  = (bid >> 4) & 63;   // 0..63  (16-px tall tiles)
    const int b   = bid >> 10;         // 0..15

    // ---- load + dequant into LDS ----
    {
        // Y: 16 blocks = 256 float4; one per thread
        const int f   = t & 127;      // float4 idx within a row of 8 blocks
        const int byr = t >> 7;       // block-row within tile (0/1)
        const int bx  = f >> 4;       // block-col within tile (0..7)
        const int e4  = f & 15;       // float4 idx within block
        const int nb  = (ty * 2 + byr) * 128 + tx * 8 + bx;
        float4 d = reinterpret_cast<const float4*>(yq)[(size_t)(b * 16384 + nb) * 16 + e4];
        float4 q = reinterpret_cast<const float4*>(ytab)[e4];
        d.x *= q.x; d.y *= q.y; d.z *= q.z; d.w *= q.w;
        const int lid = byr * 8 + bx;
        *reinterpret_cast<float4*>(&blk[lid * 72 + e4 * 4]) = d;
    }
    if (t < 128) {
        // chroma: 4 Cb blocks (threads 0..63) + 4 Cr blocks (threads 64..127)
        const int comp = t >> 6;
        const int tt   = t & 63;
        const int bx   = tt >> 4;
        const int e4   = tt & 15;
        const int nc   = ty * 64 + tx * 4 + bx;   // chroma block grid is 64x64
        const float* src = comp ? crq : cbq;
        float4 d = reinterpret_cast<const float4*>(src)[(size_t)(b * 4096 + nc) * 16 + e4];
        float4 q = reinterpret_cast<const float4*>(ctab)[e4];
        d.x *= q.x; d.y *= q.y; d.z *= q.z; d.w *= q.w;
        const int lid = 16 + comp * 4 + bx;
        *reinterpret_cast<float4*>(&blk[lid * 72 + e4 * 4]) = d;
    }
    __syncthreads();

    // ---- IDCT stage 1: t1[x][v] = sum_y X[x][y] * A8[y][v]   (thread owns row x) ----
    if (t < 192) {
        const int blki = t >> 3, x = t & 7;
        float* row = &blk[blki * 72 + x * 8];
        float4 r0 = *reinterpret_cast<float4*>(row);
        float4 r1 = *reinterpret_cast<float4*>(row + 4);
        const float xs[8] = {r0.x, r0.y, r0.z, r0.w, r1.x, r1.y, r1.z, r1.w};
        float acc[8] = {0.f, 0.f, 0.f, 0.f, 0.f, 0.f, 0.f, 0.f};
        #pragma unroll
        for (int yy = 0; yy < 8; ++yy) {
            #pragma unroll
            for (int v = 0; v < 8; ++v)
                acc[v] = fmaf(xs[yy], A8[yy][v], acc[v]);
        }
        *reinterpret_cast<float4*>(row)     = make_float4(acc[0], acc[1], acc[2], acc[3]);
        *reinterpret_cast<float4*>(row + 4) = make_float4(acc[4], acc[5], acc[6], acc[7]);
    }
    __syncthreads();

    // ---- IDCT stage 2: out[u][v] = 0.25 * sum_x t1[x][v] * A8[x][u] + 128  (thread owns col v) ----
    if (t < 192) {
        const int blki = t >> 3, v = t & 7;
        float* base = &blk[blki * 72 + v];
        float tc[8];
        #pragma unroll
        for (int x = 0; x < 8; ++x) tc[x] = base[x * 8];
        float acc[8] = {0.f, 0.f, 0.f, 0.f, 0.f, 0.f, 0.f, 0.f};
        #pragma unroll
        for (int x = 0; x < 8; ++x) {
            #pragma unroll
            for (int u = 0; u < 8; ++u)
                acc[u] = fmaf(tc[x], A8[x][u], acc[u]);
        }
        #pragma unroll
        for (int u = 0; u < 8; ++u)
            base[u * 8] = fmaf(acc[u], 0.25f, 128.0f);
    }
    __syncthreads();

    // ---- fused upsample + YCbCr->RGB + clip + store (each thread: 4 px x 3 ch) ----
    const int row = t >> 4;            // 0..15 within tile
    const int c0  = (t & 15) * 4;      // 0..60 within tile
    const int ylid = (row >> 3) * 8 + (c0 >> 3);
    const float4 yv = *reinterpret_cast<float4*>(&blk[ylid * 72 + (row & 7) * 8 + (c0 & 7)]);
    const int crow = row >> 1;         // chroma row within block (0..7)
    const int ccol = c0 >> 1;          // chroma col within 32-wide region (even)
    const int cblk = ccol >> 3;        // 0..3
    const int ce   = crow * 8 + (ccol & 7);
    const float2 cbv = *reinterpret_cast<float2*>(&blk[(16 + cblk) * 72 + ce]);
    const float2 crv = *reinterpret_cast<float2*>(&blk[(20 + cblk) * 72 + ce]);

    const float ys[4]  = {yv.x, yv.y, yv.z, yv.w};
    const float cbs[4] = {cbv.x - 128.f, cbv.x - 128.f, cbv.y - 128.f, cbv.y - 128.f};
    const float crs[4] = {crv.x - 128.f, crv.x - 128.f, crv.y - 128.f, crv.y - 128.f};

    float r[4], g[4], bl[4];
    #pragma unroll
    for (int j = 0; j < 4; ++j) {
        r[j]  = clamp255(fmaf(1.402f, crs[j], ys[j]));
        g[j]  = clamp255(fmaf(-0.714136f, crs[j], fmaf(-0.344136f, cbs[j], ys[j])));
        bl[j] = clamp255(fmaf(1.772f, cbs[j], ys[j]));
    }

    const size_t plane4 = (size_t)(1024 * 1024) >> 2;
    const size_t px4 = (((size_t)(ty * 16 + row)) * 1024 + tx * 64 + c0) >> 2;
    floatx4* o = reinterpret_cast<floatx4*>(out);
    const size_t base4 = (size_t)b * 3 * plane4 + px4;
    // Non-temporal: output is write-once, never re-read -> don't evict inputs from L3.
    floatx4 rv = {r[0],  r[1],  r[2],  r[3]};
    floatx4 gv = {g[0],  g[1],  g[2],  g[3]};
    floatx4 bv = {bl[0], bl[1], bl[2], bl[3]};
    __builtin_nontemporal_store(rv, &o[base4]);
    __builtin_nontemporal_store(gv, &o[base4 + plane4]);
    __builtin_nontemporal_store(bv, &o[base4 + 2 * plane4]);
}

extern "C" void kernel_launch(void* const* d_in, const int* in_sizes, int n_in,
                              void* d_out, int out_size, void* d_ws, size_t ws_size,
                              hipStream_t stream) {
    const float* y  = (const float*)d_in[0];
    const float* cb = (const float*)d_in[1];
    const float* cr = (const float*)d_in[2];
    const float* yt = (const float*)d_in[3];
    const float* ct = (const float*)d_in[4];
    float* out = (float*)d_out;

    // 1D grid: 16 batches x 64 tile-rows x 16 tile-cols = 16384 blocks of 256 threads
    decompress_jpeg_18021682774939_kernel<<<16384, 256, 0, stream>>>(y, cb, cr, yt, ct, out);
}